// Round 7
// baseline (347.370 us; speedup 1.0000x reference)
//
#include <hip/hip_runtime.h>

#define B_ 2
#define D_ 1024
#define T_ 2048
#define H_ 16
#define DH_ 64
#define BH_ (B_ * H_)

typedef __attribute__((ext_vector_type(8))) short bf16x8;
typedef __attribute__((ext_vector_type(8))) unsigned short u16x8;
typedef __attribute__((ext_vector_type(4))) float f32x4;

// float -> bf16 (RNE) as raw ushort
__device__ __forceinline__ unsigned short f2bf(float f) {
    unsigned u = __float_as_uint(f);
    u += 0x7fffu + ((u >> 16) & 1u);
    return (unsigned short)(u >> 16);
}

// ---------------------------------------------------------------------------
// Kernel T1: x (B,D,T) fp32 -> xT (B,T,D) bf16.  64x64 tiles through LDS.
// ---------------------------------------------------------------------------
__global__ __launch_bounds__(256) void xpose_kernel(
    const float* __restrict__ x, unsigned short* __restrict__ xT)
{
    __shared__ __align__(16) unsigned short Ls[64][68];
    const int t0 = blockIdx.x * 64;
    const int d0 = blockIdx.y * 64;
    const int b  = blockIdx.z;
    const int tid = threadIdx.x;

    const float* xb = x + (size_t)b * D_ * T_ + (size_t)d0 * T_ + t0;
    #pragma unroll
    for (int p = 0; p < 4; p++) {
        int i4  = tid + p * 256;
        int row = i4 >> 4;            // d
        int c4  = (i4 & 15) << 2;     // t
        float4 v = *(const float4*)(xb + (size_t)row * T_ + c4);
        ushort4 u;
        u.x = f2bf(v.x); u.y = f2bf(v.y); u.z = f2bf(v.z); u.w = f2bf(v.w);
        *(ushort4*)&Ls[row][c4] = u;
    }
    __syncthreads();
    unsigned short* ob = xT + (size_t)b * T_ * D_ + (size_t)t0 * D_ + d0;
    #pragma unroll
    for (int p = 0; p < 2; p++) {
        int i    = tid + p * 256;
        int orow = i >> 3;            // t
        int oc8  = (i & 7) * 8;       // d
        u16x8 tv;
        #pragma unroll
        for (int j = 0; j < 8; j++) tv[j] = Ls[oc8 + j][orow];
        *(u16x8*)(ob + (size_t)orow * D_ + oc8) = tv;
    }
}

// ---------------------------------------------------------------------------
// Kernel T2: w (3,H,D,Dh) fp32 -> wT (3,H,Dh,D) bf16.  64x64 tiles.
// ---------------------------------------------------------------------------
__global__ __launch_bounds__(256) void wpose_kernel(
    const float* __restrict__ w, unsigned short* __restrict__ wT)
{
    __shared__ __align__(16) unsigned short Ls[64][68];
    const int d0 = blockIdx.x * 64;
    const int nh = blockIdx.y;        // 0..47
    const int tid = threadIdx.x;

    const float* wb = w + (size_t)nh * D_ * DH_ + (size_t)d0 * DH_;
    #pragma unroll
    for (int p = 0; p < 4; p++) {
        int i4  = tid + p * 256;
        int row = i4 >> 4;            // d
        int c4  = (i4 & 15) << 2;     // dh
        float4 v = *(const float4*)(wb + (size_t)row * DH_ + c4);
        ushort4 u;
        u.x = f2bf(v.x); u.y = f2bf(v.y); u.z = f2bf(v.z); u.w = f2bf(v.w);
        *(ushort4*)&Ls[row][c4] = u;
    }
    __syncthreads();
    unsigned short* ob = wT + (size_t)nh * DH_ * D_ + d0;
    #pragma unroll
    for (int p = 0; p < 2; p++) {
        int i    = tid + p * 256;
        int orow = i >> 3;            // dh
        int oc8  = (i & 7) * 8;       // d
        u16x8 tv;
        #pragma unroll
        for (int j = 0; j < 8; j++) tv[j] = Ls[oc8 + j][orow];
        *(u16x8*)(ob + (size_t)orow * D_ + oc8) = tv;
    }
}

// ---------------------------------------------------------------------------
// Kernel G: QKV projection via bf16 MFMA, 128(t) x 128(dh = 2 heads) tiles.
// q outputs pre-scaled by 0.125 (exact). q,k -> qk[n][bh][t][dh];
// v -> vT[bh][dh][t] directly (transposed read-out of the LDS epilogue tile).
// ---------------------------------------------------------------------------
#define LX 72

__global__ __launch_bounds__(256) void proj_mfma_kernel(
    const unsigned short* __restrict__ xT, const unsigned short* __restrict__ wT,
    unsigned short* __restrict__ qk, unsigned short* __restrict__ vT)
{
    __shared__ __align__(16) unsigned short Buf[18432];  // 36864 B
    unsigned short* Xs = Buf;          // [128][72]
    unsigned short* Ws = Buf + 9216;   // [128][72]
    unsigned short* Es = Buf;          // [128][136] epilogue

    const int t0 = blockIdx.x * 128;
    const int y  = blockIdx.y;        // n*16 + b*8 + hp
    const int n  = y >> 4;
    const int b  = (y >> 3) & 1;
    const int hp = y & 7;             // head pair: heads 2hp, 2hp+1

    const unsigned short* xb = xT + (size_t)b * T_ * D_ + (size_t)t0 * D_;
    const unsigned short* wb = wT + (size_t)(n * 16 + 2 * hp) * DH_ * D_;

    const int tid  = threadIdx.x;
    const int wv   = tid >> 6;
    const int lane = tid & 63;
    const int c15  = lane & 15;
    const int quad = lane >> 4;
    const int tq   = (wv & 1) * 64;   // wave's t base
    const int dq   = (wv >> 1) * 64;  // wave's dh base

    f32x4 acc[4][4];
    #pragma unroll
    for (int mt = 0; mt < 4; mt++)
        #pragma unroll
        for (int nt = 0; nt < 4; nt++)
            acc[mt][nt] = (f32x4){0.f, 0.f, 0.f, 0.f};

    for (int k0 = 0; k0 < D_; k0 += 64) {
        __syncthreads();
        #pragma unroll
        for (int p = 0; p < 4; p++) {
            int i    = tid + p * 256;
            int row  = i >> 3;            // 0..127
            int col8 = (i & 7) * 8;
            *(u16x8*)&Xs[row * LX + col8] =
                *(const u16x8*)(xb + (size_t)row * D_ + k0 + col8);
            *(u16x8*)&Ws[row * LX + col8] =
                *(const u16x8*)(wb + (size_t)row * D_ + k0 + col8);
        }
        __syncthreads();

        bf16x8 af[4][2], bf[4][2];
        #pragma unroll
        for (int mt = 0; mt < 4; mt++)
            #pragma unroll
            for (int s = 0; s < 2; s++)
                af[mt][s] = *(bf16x8*)&Xs[(tq + mt * 16 + c15) * LX + quad * 8 + s * 32];
        #pragma unroll
        for (int nt = 0; nt < 4; nt++)
            #pragma unroll
            for (int s = 0; s < 2; s++)
                bf[nt][s] = *(bf16x8*)&Ws[(dq + nt * 16 + c15) * LX + quad * 8 + s * 32];

        #pragma unroll
        for (int mt = 0; mt < 4; mt++)
            #pragma unroll
            for (int nt = 0; nt < 4; nt++)
                #pragma unroll
                for (int s = 0; s < 2; s++)
                    acc[mt][nt] = __builtin_amdgcn_mfma_f32_16x16x32_bf16(
                        af[mt][s], bf[nt][s], acc[mt][nt], 0, 0, 0);
    }

    const float scale = (n == 0) ? 0.125f : 1.0f;   // fold 1/sqrt(Dh) into q
    __syncthreads();   // done reading Xs/Ws
    #pragma unroll
    for (int mt = 0; mt < 4; mt++)
        #pragma unroll
        for (int nt = 0; nt < 4; nt++)
            #pragma unroll
            for (int r = 0; r < 4; r++)
                Es[(tq + mt * 16 + quad * 4 + r) * 136 + dq + nt * 16 + c15] =
                    f2bf(acc[mt][nt][r] * scale);
    __syncthreads();

    if (n < 2) {
        #pragma unroll
        for (int p = 0; p < 8; p++) {
            int i    = tid + p * 256;
            int row  = i >> 4;            // t 0..127
            int col8 = (i & 15) * 8;      // dh 0..120
            int head = col8 >> 6;
            unsigned short* ob = qk +
                ((size_t)(n * 32 + b * 16 + 2 * hp + head) * T_ + t0 + row) * DH_ + (col8 & 63);
            *(u16x8*)ob = *(u16x8*)&Es[row * 136 + col8];
        }
    } else {
        // v: transposed read-out -> vT[bh][dh][t]
        #pragma unroll
        for (int p = 0; p < 8; p++) {
            int i    = tid + p * 256;
            int orow = i >> 4;            // dh 0..127
            int oc8  = (i & 15) * 8;      // t 0..120
            int head = orow >> 6;
            u16x8 tv;
            #pragma unroll
            for (int j = 0; j < 8; j++) tv[j] = Es[(oc8 + j) * 136 + orow];
            unsigned short* ob = vT +
                (size_t)(b * 16 + 2 * hp + head) * DH_ * T_ +
                (size_t)(orow & 63) * T_ + t0 + oc8;
            *(u16x8*)ob = tv;
        }
    }
}

// ---------------------------------------------------------------------------
// Kernel A: barrier-free flash attention, bf16 MFMA, fixed-max softmax.
// 64-q blocks, 4 waves, wave owns 16 q. K/V fragments load DIRECTLY from
// global (L1/L2-served; XCD swizzle keeps each XCD's K/V working set at
// 4 bh x 512 KB = 2 MB < 4 MB L2). LDS holds only the per-wave P buffer and
// the per-wave epilogue transpose — no __syncthreads anywhere (same-wave DS
// ordering suffices). lsum redistribution via __shfl.
// ---------------------------------------------------------------------------
#define LQ 72

__global__ __launch_bounds__(256) void attn_mfma_kernel(
    const unsigned short* __restrict__ qk, const unsigned short* __restrict__ vT,
    float* __restrict__ out)
{
    // per-wave region: 5120 B (Ps [16][72] bf16 = 2304 B; epilogue overlays
    // as [64][20] fp32 = 5120 B). + per-wave slack. Total 20480 B.
    __shared__ __align__(16) unsigned short Sm[10240];

    const int flat = blockIdx.y * 32 + blockIdx.x;   // 0..1023
    const int xcd  = flat & 7;
    const int slot = flat >> 3;                      // 0..127
    const int bh   = xcd * 4 + (slot >> 5);          // 4 bh per XCD
    const int t0   = (slot & 31) * 64;

    const unsigned short* qg = qk + ((size_t)bh * T_ + t0) * DH_;   // pre-scaled q
    const unsigned short* kg = qk + ((size_t)(BH_ + bh) * T_) * DH_;
    const unsigned short* vg = vT + (size_t)bh * DH_ * T_;          // [dh][t]

    const int tid  = threadIdx.x;
    const int wv   = tid >> 6;
    const int lane = tid & 63;
    const int c15  = lane & 15;
    const int quad = lane >> 4;

    unsigned short* Ps  = Sm + wv * 2560;            // [16][72] bf16
    float*          Osw = (float*)(Sm + wv * 2560);  // [64][20] fp32 (epilogue)

    // Q^T B-fragments straight from global: B[k=dh][n=qrow]
    bf16x8 bq[2];
    #pragma unroll
    for (int s = 0; s < 2; s++)
        bq[s] = *(const bf16x8*)(qg + (size_t)(wv * 16 + c15) * DH_ + quad * 8 + s * 32);

    float lsum = 0.f;
    f32x4 Oacc[4];
    #pragma unroll
    for (int nt = 0; nt < 4; nt++) Oacc[nt] = (f32x4){0.f, 0.f, 0.f, 0.f};

    for (int tau = 0; tau < T_; tau += 64) {
        // S^T = K Q^T per 16-key block; exp; packed b64 P write
        #pragma unroll
        for (int mt = 0; mt < 4; mt++) {
            f32x4 sa = (f32x4){0.f, 0.f, 0.f, 0.f};
            #pragma unroll
            for (int s = 0; s < 2; s++) {
                bf16x8 ak = *(const bf16x8*)(kg +
                    (size_t)(tau + mt * 16 + c15) * DH_ + quad * 8 + s * 32);
                sa = __builtin_amdgcn_mfma_f32_16x16x32_bf16(ak, bq[s], sa, 0, 0, 0);
            }
            float p0 = __expf(sa[0]);
            float p1 = __expf(sa[1]);
            float p2 = __expf(sa[2]);
            float p3 = __expf(sa[3]);
            lsum += (p0 + p1) + (p2 + p3);
            uint2 pk;
            pk.x = (unsigned)f2bf(p0) | ((unsigned)f2bf(p1) << 16);
            pk.y = (unsigned)f2bf(p2) | ((unsigned)f2bf(p3) << 16);
            *(uint2*)&Ps[c15 * LQ + mt * 16 + quad * 4] = pk;
        }

        // O += P V : A = P rows (same-wave LDS, in-order DS pipe), B = V^T
        #pragma unroll
        for (int s = 0; s < 2; s++) {
            bf16x8 ap = *(bf16x8*)&Ps[c15 * LQ + quad * 8 + s * 32];
            #pragma unroll
            for (int nt = 0; nt < 4; nt++) {
                bf16x8 bv = *(const bf16x8*)(vg +
                    (size_t)(nt * 16 + c15) * T_ + tau + quad * 8 + s * 32);
                Oacc[nt] = __builtin_amdgcn_mfma_f32_16x16x32_bf16(ap, bv, Oacc[nt], 0, 0, 0);
            }
        }
    }

    // row sums: reduce across quads, then fetch L[quad*4+r] via shfl
    lsum += __shfl_xor(lsum, 16);
    lsum += __shfl_xor(lsum, 32);
    float linv[4];
    #pragma unroll
    for (int r = 0; r < 4; r++)
        linv[r] = 1.0f / __shfl(lsum, quad * 4 + r);

    // epilogue: per-wave LDS transpose (overlays Ps; same-wave ordering)
    #pragma unroll
    for (int nt = 0; nt < 4; nt++)
        #pragma unroll
        for (int r = 0; r < 4; r++)
            Osw[(nt * 16 + c15) * 20 + quad * 4 + r] = Oacc[nt][r] * linv[r];

    const int b = bh >> 4, h = bh & 15;
    float* og = out + (size_t)b * D_ * T_ + (size_t)(h * DH_) * T_ + t0 + wv * 16;
    #pragma unroll
    for (int p = 0; p < 4; p++) {
        int idx = lane + p * 64;
        int dh  = idx >> 2;          // 0..63
        int qs  = (idx & 3) * 4;     // 0,4,8,12
        float4 v = *(float4*)&Osw[dh * 20 + qs];
        *(float4*)(og + (size_t)dh * T_ + qs) = v;
    }
}

extern "C" void kernel_launch(void* const* d_in, const int* in_sizes, int n_in,
                              void* d_out, int out_size, void* d_ws, size_t ws_size,
                              hipStream_t stream)
{
    const float* x = (const float*)d_in[0];   // (B, D, T) fp32
    const float* w = (const float*)d_in[1];   // (3, H, D, Dh) fp32
    float* out = (float*)d_out;               // (B, D, T) fp32

    // ws layout:
    unsigned short* qk = (unsigned short*)d_ws;                           // [2][32][T][64] bf16 = 16 MB (+8 MB slack)
    unsigned short* vT = (unsigned short*)((char*)d_ws + (24u << 20));    // [32][64][T] bf16 = 8 MB
    unsigned short* xT = (unsigned short*)((char*)d_ws + (32u << 20));    // [B][T][D] bf16 = 8 MB
    unsigned short* wT = (unsigned short*)((char*)d_ws + (40u << 20));    // [3][H][64][D] bf16 = 6 MB

    xpose_kernel<<<dim3(T_ / 64, D_ / 64, B_), 256, 0, stream>>>(x, xT);
    wpose_kernel<<<dim3(D_ / 64, 3 * H_), 256, 0, stream>>>(w, wT);
    proj_mfma_kernel<<<dim3(T_ / 128, 48), 256, 0, stream>>>(xT, wT, qk, vT);
    attn_mfma_kernel<<<dim3(32, 32), 256, 0, stream>>>(qk, vT, out);
}

// Round 8
// 186.914 us; speedup vs baseline: 1.8585x; 1.8585x over previous
//
#include <hip/hip_runtime.h>

#define B_ 2
#define D_ 1024
#define T_ 2048
#define H_ 16
#define DH_ 64
#define BH_ (B_ * H_)

typedef __attribute__((ext_vector_type(8))) short bf16x8;
typedef __attribute__((ext_vector_type(8))) unsigned short u16x8;
typedef __attribute__((ext_vector_type(4))) float f32x4;

// float -> bf16 (RNE) as raw ushort
__device__ __forceinline__ unsigned short f2bf(float f) {
    unsigned u = __float_as_uint(f);
    u += 0x7fffu + ((u >> 16) & 1u);
    return (unsigned short)(u >> 16);
}

// ---------------------------------------------------------------------------
// Kernel T1: x (B,D,T) fp32 -> xT (B,T,D) bf16.  64x64 tiles through LDS.
// ---------------------------------------------------------------------------
__global__ __launch_bounds__(256) void xpose_kernel(
    const float* __restrict__ x, unsigned short* __restrict__ xT)
{
    __shared__ __align__(16) unsigned short Ls[64][68];
    const int t0 = blockIdx.x * 64;
    const int d0 = blockIdx.y * 64;
    const int b  = blockIdx.z;
    const int tid = threadIdx.x;

    const float* xb = x + (size_t)b * D_ * T_ + (size_t)d0 * T_ + t0;
    #pragma unroll
    for (int p = 0; p < 4; p++) {
        int i4  = tid + p * 256;
        int row = i4 >> 4;            // d
        int c4  = (i4 & 15) << 2;     // t
        float4 v = *(const float4*)(xb + (size_t)row * T_ + c4);
        ushort4 u;
        u.x = f2bf(v.x); u.y = f2bf(v.y); u.z = f2bf(v.z); u.w = f2bf(v.w);
        *(ushort4*)&Ls[row][c4] = u;
    }
    __syncthreads();
    unsigned short* ob = xT + (size_t)b * T_ * D_ + (size_t)t0 * D_ + d0;
    #pragma unroll
    for (int p = 0; p < 2; p++) {
        int i    = tid + p * 256;
        int orow = i >> 3;            // t
        int oc8  = (i & 7) * 8;       // d
        u16x8 tv;
        #pragma unroll
        for (int j = 0; j < 8; j++) tv[j] = Ls[oc8 + j][orow];
        *(u16x8*)(ob + (size_t)orow * D_ + oc8) = tv;
    }
}

// ---------------------------------------------------------------------------
// Kernel T2: w (3,H,D,Dh) fp32 -> wT (3,H,Dh,D) bf16.  64x64 tiles.
// ---------------------------------------------------------------------------
__global__ __launch_bounds__(256) void wpose_kernel(
    const float* __restrict__ w, unsigned short* __restrict__ wT)
{
    __shared__ __align__(16) unsigned short Ls[64][68];
    const int d0 = blockIdx.x * 64;
    const int nh = blockIdx.y;        // 0..47
    const int tid = threadIdx.x;

    const float* wb = w + (size_t)nh * D_ * DH_ + (size_t)d0 * DH_;
    #pragma unroll
    for (int p = 0; p < 4; p++) {
        int i4  = tid + p * 256;
        int row = i4 >> 4;            // d
        int c4  = (i4 & 15) << 2;     // dh
        float4 v = *(const float4*)(wb + (size_t)row * DH_ + c4);
        ushort4 u;
        u.x = f2bf(v.x); u.y = f2bf(v.y); u.z = f2bf(v.z); u.w = f2bf(v.w);
        *(ushort4*)&Ls[row][c4] = u;
    }
    __syncthreads();
    unsigned short* ob = wT + (size_t)nh * DH_ * D_ + d0;
    #pragma unroll
    for (int p = 0; p < 2; p++) {
        int i    = tid + p * 256;
        int orow = i >> 3;            // dh
        int oc8  = (i & 7) * 8;       // d
        u16x8 tv;
        #pragma unroll
        for (int j = 0; j < 8; j++) tv[j] = Ls[oc8 + j][orow];
        *(u16x8*)(ob + (size_t)orow * D_ + oc8) = tv;
    }
}

// ---------------------------------------------------------------------------
// Kernel G: QKV projection via bf16 MFMA, 128(t) x 128(dh = 2 heads) tiles.
// q outputs pre-scaled by 0.125 (exact). q,k -> qk[n][bh][t][dh];
// v -> vT[bh][dh][t] directly (transposed read-out of the LDS epilogue tile).
// ---------------------------------------------------------------------------
#define LX 72

__global__ __launch_bounds__(256) void proj_mfma_kernel(
    const unsigned short* __restrict__ xT, const unsigned short* __restrict__ wT,
    unsigned short* __restrict__ qk, unsigned short* __restrict__ vT)
{
    __shared__ __align__(16) unsigned short Buf[18432];  // 36864 B
    unsigned short* Xs = Buf;          // [128][72]
    unsigned short* Ws = Buf + 9216;   // [128][72]
    unsigned short* Es = Buf;          // [128][136] epilogue

    const int t0 = blockIdx.x * 128;
    const int y  = blockIdx.y;        // n*16 + b*8 + hp
    const int n  = y >> 4;
    const int b  = (y >> 3) & 1;
    const int hp = y & 7;             // head pair: heads 2hp, 2hp+1

    const unsigned short* xb = xT + (size_t)b * T_ * D_ + (size_t)t0 * D_;
    const unsigned short* wb = wT + (size_t)(n * 16 + 2 * hp) * DH_ * D_;

    const int tid  = threadIdx.x;
    const int wv   = tid >> 6;
    const int lane = tid & 63;
    const int c15  = lane & 15;
    const int quad = lane >> 4;
    const int tq   = (wv & 1) * 64;   // wave's t base
    const int dq   = (wv >> 1) * 64;  // wave's dh base

    f32x4 acc[4][4];
    #pragma unroll
    for (int mt = 0; mt < 4; mt++)
        #pragma unroll
        for (int nt = 0; nt < 4; nt++)
            acc[mt][nt] = (f32x4){0.f, 0.f, 0.f, 0.f};

    for (int k0 = 0; k0 < D_; k0 += 64) {
        __syncthreads();
        #pragma unroll
        for (int p = 0; p < 4; p++) {
            int i    = tid + p * 256;
            int row  = i >> 3;            // 0..127
            int col8 = (i & 7) * 8;
            *(u16x8*)&Xs[row * LX + col8] =
                *(const u16x8*)(xb + (size_t)row * D_ + k0 + col8);
            *(u16x8*)&Ws[row * LX + col8] =
                *(const u16x8*)(wb + (size_t)row * D_ + k0 + col8);
        }
        __syncthreads();

        bf16x8 af[4][2], bf[4][2];
        #pragma unroll
        for (int mt = 0; mt < 4; mt++)
            #pragma unroll
            for (int s = 0; s < 2; s++)
                af[mt][s] = *(bf16x8*)&Xs[(tq + mt * 16 + c15) * LX + quad * 8 + s * 32];
        #pragma unroll
        for (int nt = 0; nt < 4; nt++)
            #pragma unroll
            for (int s = 0; s < 2; s++)
                bf[nt][s] = *(bf16x8*)&Ws[(dq + nt * 16 + c15) * LX + quad * 8 + s * 32];

        #pragma unroll
        for (int mt = 0; mt < 4; mt++)
            #pragma unroll
            for (int nt = 0; nt < 4; nt++)
                #pragma unroll
                for (int s = 0; s < 2; s++)
                    acc[mt][nt] = __builtin_amdgcn_mfma_f32_16x16x32_bf16(
                        af[mt][s], bf[nt][s], acc[mt][nt], 0, 0, 0);
    }

    const float scale = (n == 0) ? 0.125f : 1.0f;   // fold 1/sqrt(Dh) into q
    __syncthreads();   // done reading Xs/Ws
    #pragma unroll
    for (int mt = 0; mt < 4; mt++)
        #pragma unroll
        for (int nt = 0; nt < 4; nt++)
            #pragma unroll
            for (int r = 0; r < 4; r++)
                Es[(tq + mt * 16 + quad * 4 + r) * 136 + dq + nt * 16 + c15] =
                    f2bf(acc[mt][nt][r] * scale);
    __syncthreads();

    if (n < 2) {
        #pragma unroll
        for (int p = 0; p < 8; p++) {
            int i    = tid + p * 256;
            int row  = i >> 4;            // t 0..127
            int col8 = (i & 15) * 8;      // dh 0..120
            int head = col8 >> 6;
            unsigned short* ob = qk +
                ((size_t)(n * 32 + b * 16 + 2 * hp + head) * T_ + t0 + row) * DH_ + (col8 & 63);
            *(u16x8*)ob = *(u16x8*)&Es[row * 136 + col8];
        }
    } else {
        // v: transposed read-out -> vT[bh][dh][t]
        #pragma unroll
        for (int p = 0; p < 8; p++) {
            int i    = tid + p * 256;
            int orow = i >> 4;            // dh 0..127
            int oc8  = (i & 15) * 8;      // t 0..120
            int head = orow >> 6;
            u16x8 tv;
            #pragma unroll
            for (int j = 0; j < 8; j++) tv[j] = Es[(oc8 + j) * 136 + orow];
            unsigned short* ob = vT +
                (size_t)(b * 16 + 2 * hp + head) * DH_ * T_ +
                (size_t)(orow & 63) * T_ + t0 + oc8;
            *(u16x8*)ob = tv;
        }
    }
}

// ---------------------------------------------------------------------------
// Kernel A: flash attention, bf16 MFMA, fixed-max softmax.
// 64-q blocks (grid 1024 -> 4 blocks/CU, 16 waves/CU), 4 waves, wave owns
// 16 q. K/V staged in shared LDS tiles (round-5/6 proven staging); P buffer
// is PER-WAVE (same-wave DS ordering -> no third barrier). S^T = K*Q^T so
// P writes are packed b64 and PV A-fragments are contiguous b128 (round-6
// proven core). Q fragments direct from global, loaded once. Only 2
// __syncthreads per iteration. ak/bv loaded just-in-time to bound VGPRs.
// ---------------------------------------------------------------------------
#define LQ 72

__global__ __launch_bounds__(256, 4) void attn_mfma_kernel(
    const unsigned short* __restrict__ qk, const unsigned short* __restrict__ vT,
    float* __restrict__ out)
{
    __shared__ __align__(16) unsigned short Sm[13824];   // 27648 B
    unsigned short* Ks  = Sm;            // [64][72]
    unsigned short* Vs  = Sm + 4608;     // [64][72] row = dh
    unsigned short* Psb = Sm + 9216;     // 4 x [16][72] per-wave

    const int flat = blockIdx.x;                     // 0..1023
    const int bh   = (flat & 7) * 4 + ((flat >> 3) >> 5);   // XCD swizzle: 4 bh/XCD
    const int t0   = ((flat >> 3) & 31) * 64;

    const unsigned short* qg = qk + ((size_t)bh * T_ + t0) * DH_;   // pre-scaled q
    const unsigned short* kg = qk + ((size_t)(BH_ + bh) * T_) * DH_;
    const unsigned short* vg = vT + (size_t)bh * DH_ * T_;          // [dh][t]

    const int tid  = threadIdx.x;
    const int wv   = tid >> 6;
    const int lane = tid & 63;
    const int c15  = lane & 15;
    const int quad = lane >> 4;

    unsigned short* Ps = Psb + wv * 1152;    // [16][72] bf16 (2304 B)

    // Q^T B-fragments straight from global: wave owns q rows wv*16..+16
    bf16x8 bq[2];
    #pragma unroll
    for (int s = 0; s < 2; s++)
        bq[s] = *(const bf16x8*)(qg + (size_t)(wv * 16 + c15) * DH_ + quad * 8 + s * 32);

    float lsum = 0.f;
    f32x4 Oacc[4];
    #pragma unroll
    for (int nt = 0; nt < 4; nt++) Oacc[nt] = (f32x4){0.f, 0.f, 0.f, 0.f};

    for (int tau = 0; tau < T_; tau += 64) {
        __syncthreads();   // A: all waves' PV reads of Ks/Vs are done
        #pragma unroll
        for (int p = 0; p < 2; p++) {
            int i    = tid + p * 256;
            int row  = i >> 3;            // 0..63
            int col8 = (i & 7) * 8;
            *(u16x8*)&Ks[row * LQ + col8] =
                *(const u16x8*)(kg + (size_t)(tau + row) * DH_ + col8);
            *(u16x8*)&Vs[row * LQ + col8] =
                *(const u16x8*)(vg + (size_t)row * T_ + tau + col8);
        }
        __syncthreads();   // B: tiles staged

        // S^T = K Q^T per 16-key block; exp; packed b64 write to own-wave Ps
        #pragma unroll
        for (int mt = 0; mt < 4; mt++) {
            f32x4 sa = (f32x4){0.f, 0.f, 0.f, 0.f};
            #pragma unroll
            for (int s = 0; s < 2; s++) {
                bf16x8 ak = *(bf16x8*)&Ks[(mt * 16 + c15) * LQ + quad * 8 + s * 32];
                sa = __builtin_amdgcn_mfma_f32_16x16x32_bf16(ak, bq[s], sa, 0, 0, 0);
            }
            float p0 = __expf(sa[0]);
            float p1 = __expf(sa[1]);
            float p2 = __expf(sa[2]);
            float p3 = __expf(sa[3]);
            lsum += (p0 + p1) + (p2 + p3);
            uint2 pk;
            pk.x = (unsigned)f2bf(p0) | ((unsigned)f2bf(p1) << 16);
            pk.y = (unsigned)f2bf(p2) | ((unsigned)f2bf(p3) << 16);
            *(uint2*)&Ps[c15 * LQ + mt * 16 + quad * 4] = pk;
        }
        // no barrier: Ps is per-wave; DS ops within a wave are in-order

        // O += P V : A = P rows (b128 own-wave), B = V^T fragments from Vs
        #pragma unroll
        for (int s = 0; s < 2; s++) {
            bf16x8 ap = *(bf16x8*)&Ps[c15 * LQ + quad * 8 + s * 32];
            #pragma unroll
            for (int nt = 0; nt < 4; nt++) {
                bf16x8 bv = *(bf16x8*)&Vs[(nt * 16 + c15) * LQ + quad * 8 + s * 32];
                Oacc[nt] = __builtin_amdgcn_mfma_f32_16x16x32_bf16(ap, bv, Oacc[nt], 0, 0, 0);
            }
        }
    }

    // row sums: reduce across quads, then fetch L[quad*4+r] via shfl
    lsum += __shfl_xor(lsum, 16);
    lsum += __shfl_xor(lsum, 32);
    float linv[4];
    #pragma unroll
    for (int r = 0; r < 4; r++)
        linv[r] = 1.0f / __shfl(lsum, quad * 4 + r);

    // epilogue: per-wave transpose through LDS region wv*4608 B ([64][17] f32)
    __syncthreads();   // all waves done reading Ks/Vs
    float* Osw = (float*)((char*)(void*)Sm + wv * 4608);
    #pragma unroll
    for (int nt = 0; nt < 4; nt++)
        #pragma unroll
        for (int r = 0; r < 4; r++)
            Osw[(nt * 16 + c15) * 17 + quad * 4 + r] = Oacc[nt][r] * linv[r];

    const int b = bh >> 4, h = bh & 15;
    float* og = out + (size_t)b * D_ * T_ + (size_t)(h * DH_) * T_ + t0 + wv * 16;
    #pragma unroll
    for (int p = 0; p < 4; p++) {
        int idx = lane + p * 64;
        int dh  = idx >> 2;          // 0..63
        int qs  = (idx & 3) * 4;     // 0,4,8,12
        float4 v = *(float4*)&Osw[dh * 17 + qs];
        *(float4*)(og + (size_t)dh * T_ + qs) = v;
    }
}

extern "C" void kernel_launch(void* const* d_in, const int* in_sizes, int n_in,
                              void* d_out, int out_size, void* d_ws, size_t ws_size,
                              hipStream_t stream)
{
    const float* x = (const float*)d_in[0];   // (B, D, T) fp32
    const float* w = (const float*)d_in[1];   // (3, H, D, Dh) fp32
    float* out = (float*)d_out;               // (B, D, T) fp32

    // ws layout:
    unsigned short* qk = (unsigned short*)d_ws;                           // [2][32][T][64] bf16 = 16 MB (+8 MB slack)
    unsigned short* vT = (unsigned short*)((char*)d_ws + (24u << 20));    // [32][64][T] bf16 = 8 MB
    unsigned short* xT = (unsigned short*)((char*)d_ws + (32u << 20));    // [B][T][D] bf16 = 8 MB
    unsigned short* wT = (unsigned short*)((char*)d_ws + (40u << 20));    // [3][H][64][D] bf16 = 6 MB

    xpose_kernel<<<dim3(T_ / 64, D_ / 64, B_), 256, 0, stream>>>(x, xT);
    wpose_kernel<<<dim3(D_ / 64, 3 * H_), 256, 0, stream>>>(w, wT);
    proj_mfma_kernel<<<dim3(T_ / 128, 48), 256, 0, stream>>>(xT, wT, qk, vT);
    attn_mfma_kernel<<<1024, 256, 0, stream>>>(qk, vT, out);
}

// Round 9
// 175.797 us; speedup vs baseline: 1.9760x; 1.0632x over previous
//
#include <hip/hip_runtime.h>

#define B_ 2
#define D_ 1024
#define T_ 2048
#define H_ 16
#define DH_ 64
#define BH_ (B_ * H_)

typedef __attribute__((ext_vector_type(8))) short bf16x8;
typedef __attribute__((ext_vector_type(8))) unsigned short u16x8;
typedef __attribute__((ext_vector_type(4))) float f32x4;

// float -> bf16 (RNE) as raw ushort
__device__ __forceinline__ unsigned short f2bf(float f) {
    unsigned u = __float_as_uint(f);
    u += 0x7fffu + ((u >> 16) & 1u);
    return (unsigned short)(u >> 16);
}

// ---------------------------------------------------------------------------
// Kernel T1: x (B,D,T) fp32 -> xT (B,T,D) bf16.  64x64 tiles through LDS.
// ---------------------------------------------------------------------------
__global__ __launch_bounds__(256) void xpose_kernel(
    const float* __restrict__ x, unsigned short* __restrict__ xT)
{
    __shared__ __align__(16) unsigned short Ls[64][68];
    const int t0 = blockIdx.x * 64;
    const int d0 = blockIdx.y * 64;
    const int b  = blockIdx.z;
    const int tid = threadIdx.x;

    const float* xb = x + (size_t)b * D_ * T_ + (size_t)d0 * T_ + t0;
    #pragma unroll
    for (int p = 0; p < 4; p++) {
        int i4  = tid + p * 256;
        int row = i4 >> 4;            // d
        int c4  = (i4 & 15) << 2;     // t
        float4 v = *(const float4*)(xb + (size_t)row * T_ + c4);
        ushort4 u;
        u.x = f2bf(v.x); u.y = f2bf(v.y); u.z = f2bf(v.z); u.w = f2bf(v.w);
        *(ushort4*)&Ls[row][c4] = u;
    }
    __syncthreads();
    unsigned short* ob = xT + (size_t)b * T_ * D_ + (size_t)t0 * D_ + d0;
    #pragma unroll
    for (int p = 0; p < 2; p++) {
        int i    = tid + p * 256;
        int orow = i >> 3;            // t
        int oc8  = (i & 7) * 8;       // d
        u16x8 tv;
        #pragma unroll
        for (int j = 0; j < 8; j++) tv[j] = Ls[oc8 + j][orow];
        *(u16x8*)(ob + (size_t)orow * D_ + oc8) = tv;
    }
}

// ---------------------------------------------------------------------------
// Kernel T2: w (3,H,D,Dh) fp32 -> wT (3,H,Dh,D) bf16.  64x64 tiles.
// ---------------------------------------------------------------------------
__global__ __launch_bounds__(256) void wpose_kernel(
    const float* __restrict__ w, unsigned short* __restrict__ wT)
{
    __shared__ __align__(16) unsigned short Ls[64][68];
    const int d0 = blockIdx.x * 64;
    const int nh = blockIdx.y;        // 0..47
    const int tid = threadIdx.x;

    const float* wb = w + (size_t)nh * D_ * DH_ + (size_t)d0 * DH_;
    #pragma unroll
    for (int p = 0; p < 4; p++) {
        int i4  = tid + p * 256;
        int row = i4 >> 4;            // d
        int c4  = (i4 & 15) << 2;     // dh
        float4 v = *(const float4*)(wb + (size_t)row * DH_ + c4);
        ushort4 u;
        u.x = f2bf(v.x); u.y = f2bf(v.y); u.z = f2bf(v.z); u.w = f2bf(v.w);
        *(ushort4*)&Ls[row][c4] = u;
    }
    __syncthreads();
    unsigned short* ob = wT + (size_t)nh * DH_ * D_ + d0;
    #pragma unroll
    for (int p = 0; p < 2; p++) {
        int i    = tid + p * 256;
        int orow = i >> 3;            // dh
        int oc8  = (i & 7) * 8;       // d
        u16x8 tv;
        #pragma unroll
        for (int j = 0; j < 8; j++) tv[j] = Ls[oc8 + j][orow];
        *(u16x8*)(ob + (size_t)orow * D_ + oc8) = tv;
    }
}

// ---------------------------------------------------------------------------
// Kernel G: QKV projection via bf16 MFMA, 128(t) x 128(dh = 2 heads) tiles.
// LX=80 (160 B rows, 16-B aligned -> true b128 LDS ops). Register-prefetch
// pipeline: global loads for k+1 issue before the MFMA block of k.
// q outputs pre-scaled by 0.125; q,k -> qk[n][bh][t][dh]; v -> vT[bh][dh][t].
// ---------------------------------------------------------------------------
#define LX 80

__global__ __launch_bounds__(256, 3) void proj_mfma_kernel(
    const unsigned short* __restrict__ xT, const unsigned short* __restrict__ wT,
    unsigned short* __restrict__ qk, unsigned short* __restrict__ vT)
{
    __shared__ __align__(16) unsigned short Buf[20480];  // 40960 B
    unsigned short* Xs = Buf;           // [128][80]
    unsigned short* Ws = Buf + 10240;   // [128][80]
    unsigned short* Es = Buf;           // [128][136] epilogue (34816 shorts? no: fits: 17408 shorts)

    const int t0 = blockIdx.x * 128;
    const int y  = blockIdx.y;        // n*16 + b*8 + hp
    const int n  = y >> 4;
    const int b  = (y >> 3) & 1;
    const int hp = y & 7;             // head pair: heads 2hp, 2hp+1

    const unsigned short* xb = xT + (size_t)b * T_ * D_ + (size_t)t0 * D_;
    const unsigned short* wb = wT + (size_t)(n * 16 + 2 * hp) * DH_ * D_;

    const int tid  = threadIdx.x;
    const int wv   = tid >> 6;
    const int lane = tid & 63;
    const int c15  = lane & 15;
    const int quad = lane >> 4;
    const int tq   = (wv & 1) * 64;   // wave's t base
    const int dq   = (wv >> 1) * 64;  // wave's dh base

    const int srow = tid >> 3;        // 0..31
    const int scol = (tid & 7) * 8;   // 0..56

    f32x4 acc[4][4];
    #pragma unroll
    for (int mt = 0; mt < 4; mt++)
        #pragma unroll
        for (int nt = 0; nt < 4; nt++)
            acc[mt][nt] = (f32x4){0.f, 0.f, 0.f, 0.f};

    // prefetch tile k0=0
    u16x8 xreg[4], wreg[4];
    #pragma unroll
    for (int p = 0; p < 4; p++) {
        int row = srow + p * 32;
        xreg[p] = *(const u16x8*)(xb + (size_t)row * D_ + scol);
        wreg[p] = *(const u16x8*)(wb + (size_t)row * D_ + scol);
    }

    for (int k0 = 0; k0 < D_; k0 += 64) {
        __syncthreads();   // previous compute done reading Xs/Ws
        #pragma unroll
        for (int p = 0; p < 4; p++) {
            int row = srow + p * 32;
            *(u16x8*)&Xs[row * LX + scol] = xreg[p];
            *(u16x8*)&Ws[row * LX + scol] = wreg[p];
        }
        __syncthreads();   // tile staged

        if (k0 + 64 < D_) {
            #pragma unroll
            for (int p = 0; p < 4; p++) {
                int row = srow + p * 32;
                xreg[p] = *(const u16x8*)(xb + (size_t)row * D_ + k0 + 64 + scol);
                wreg[p] = *(const u16x8*)(wb + (size_t)row * D_ + k0 + 64 + scol);
            }
        }

        bf16x8 af[4][2], bf[4][2];
        #pragma unroll
        for (int mt = 0; mt < 4; mt++)
            #pragma unroll
            for (int s = 0; s < 2; s++)
                af[mt][s] = *(bf16x8*)&Xs[(tq + mt * 16 + c15) * LX + quad * 8 + s * 32];
        #pragma unroll
        for (int nt = 0; nt < 4; nt++)
            #pragma unroll
            for (int s = 0; s < 2; s++)
                bf[nt][s] = *(bf16x8*)&Ws[(dq + nt * 16 + c15) * LX + quad * 8 + s * 32];

        #pragma unroll
        for (int mt = 0; mt < 4; mt++)
            #pragma unroll
            for (int nt = 0; nt < 4; nt++)
                #pragma unroll
                for (int s = 0; s < 2; s++)
                    acc[mt][nt] = __builtin_amdgcn_mfma_f32_16x16x32_bf16(
                        af[mt][s], bf[nt][s], acc[mt][nt], 0, 0, 0);
    }

    const float scale = (n == 0) ? 0.125f : 1.0f;   // fold 1/sqrt(Dh) into q
    __syncthreads();   // done reading Xs/Ws
    #pragma unroll
    for (int mt = 0; mt < 4; mt++)
        #pragma unroll
        for (int nt = 0; nt < 4; nt++)
            #pragma unroll
            for (int r = 0; r < 4; r++)
                Es[(tq + mt * 16 + quad * 4 + r) * 136 + dq + nt * 16 + c15] =
                    f2bf(acc[mt][nt][r] * scale);
    __syncthreads();

    if (n < 2) {
        #pragma unroll
        for (int p = 0; p < 8; p++) {
            int i    = tid + p * 256;
            int row  = i >> 4;            // t 0..127
            int col8 = (i & 15) * 8;      // dh 0..120
            int head = col8 >> 6;
            unsigned short* ob = qk +
                ((size_t)(n * 32 + b * 16 + 2 * hp + head) * T_ + t0 + row) * DH_ + (col8 & 63);
            *(u16x8*)ob = *(u16x8*)&Es[row * 136 + col8];
        }
    } else {
        // v: transposed read-out -> vT[bh][dh][t]
        #pragma unroll
        for (int p = 0; p < 8; p++) {
            int i    = tid + p * 256;
            int orow = i >> 4;            // dh 0..127
            int oc8  = (i & 15) * 8;      // t 0..120
            int head = orow >> 6;
            u16x8 tv;
            #pragma unroll
            for (int j = 0; j < 8; j++) tv[j] = Es[(oc8 + j) * 136 + orow];
            unsigned short* ob = vT +
                (size_t)(b * 16 + 2 * hp + head) * DH_ * T_ +
                (size_t)(orow & 63) * T_ + t0 + oc8;
            *(u16x8*)ob = tv;
        }
    }
}

// ---------------------------------------------------------------------------
// Kernel A: flash attention, bf16 MFMA, fixed-max softmax.
// 128-q blocks (grid 512 -> 2 blocks/CU), 4 waves, wave owns 32 q (2 groups
// of 16). K/V double-buffered [64][64] (128 B rows, aligned b128) with
// register prefetch -> ONE barrier per iteration. P per-wave [32][64] with
// XOR swizzle (^ (c15&7)*8) -> conflict-free b64 writes / b128 reads.
// ---------------------------------------------------------------------------
__global__ __launch_bounds__(256, 2) void attn_mfma_kernel(
    const unsigned short* __restrict__ qk, const unsigned short* __restrict__ vT,
    float* __restrict__ out)
{
    // shorts: Ks0[0,4096) Vs0[4096,8192) Ks1[8192,12288) Vs1[12288,16384)
    //         P 4 x [32][64] at [16384, 24576).  Total 49152 B.
    __shared__ __align__(16) unsigned short Sm[24576];

    const int flat = blockIdx.x;                     // 0..511
    const int bh   = (flat & 7) * 4 + ((flat >> 3) >> 4);   // XCD swizzle: 4 bh/XCD
    const int t0   = ((flat >> 3) & 15) * 128;

    const unsigned short* qg = qk + ((size_t)bh * T_ + t0) * DH_;   // pre-scaled q
    const unsigned short* kg = qk + ((size_t)(BH_ + bh) * T_) * DH_;
    const unsigned short* vg = vT + (size_t)bh * DH_ * T_;          // [dh][t]

    const int tid  = threadIdx.x;
    const int wv   = tid >> 6;
    const int lane = tid & 63;
    const int c15  = lane & 15;
    const int quad = lane >> 4;
    const int swz  = (c15 & 7) * 8;

    unsigned short* Ps = Sm + 16384 + wv * 2048;     // [32][64]

    const int srow = tid >> 3;        // 0..31
    const int scol = (tid & 7) * 8;   // 0..56

    // Q^T B-fragments straight from global: wave owns q rows wv*32 .. +32
    bf16x8 bq[2][2];
    #pragma unroll
    for (int g = 0; g < 2; g++)
        #pragma unroll
        for (int s = 0; s < 2; s++)
            bq[g][s] = *(const bf16x8*)(qg +
                (size_t)(wv * 32 + g * 16 + c15) * DH_ + quad * 8 + s * 32);

    float lsum[2] = {0.f, 0.f};
    f32x4 Oacc[2][4];
    #pragma unroll
    for (int g = 0; g < 2; g++)
        #pragma unroll
        for (int nt = 0; nt < 4; nt++)
            Oacc[g][nt] = (f32x4){0.f, 0.f, 0.f, 0.f};

    // preload tile 0 and stage into buffer 0 (no prior readers)
    u16x8 kreg[2], vreg[2];
    #pragma unroll
    for (int p = 0; p < 2; p++) {
        int row = srow + p * 32;
        kreg[p] = *(const u16x8*)(kg + (size_t)row * DH_ + scol);
        vreg[p] = *(const u16x8*)(vg + (size_t)row * T_ + scol);
    }
    #pragma unroll
    for (int p = 0; p < 2; p++) {
        int row = srow + p * 32;
        *(u16x8*)&Sm[row * 64 + scol]        = kreg[p];
        *(u16x8*)&Sm[4096 + row * 64 + scol] = vreg[p];
    }

    for (int tau = 0; tau < T_; tau += 64) {
        const int cur = (tau >> 6) & 1;
        unsigned short* Ks = Sm + cur * 8192;
        unsigned short* Vs = Ks + 4096;
        __syncthreads();   // tile tau staged by all waves; buf[1-cur] free for writes

        const bool pf = (tau + 64 < T_);
        if (pf) {   // issue global loads for tile tau+1 early (latency overlap)
            #pragma unroll
            for (int p = 0; p < 2; p++) {
                int row = srow + p * 32;
                kreg[p] = *(const u16x8*)(kg + (size_t)(tau + 64 + row) * DH_ + scol);
                vreg[p] = *(const u16x8*)(vg + (size_t)row * T_ + tau + 64 + scol);
            }
        }

        // K A-fragments (shared across both q-groups)
        bf16x8 ak[4][2];
        #pragma unroll
        for (int mt = 0; mt < 4; mt++)
            #pragma unroll
            for (int s = 0; s < 2; s++)
                ak[mt][s] = *(bf16x8*)&Ks[(mt * 16 + c15) * 64 + quad * 8 + s * 32];

        // S^T = K Q^T; exp; swizzled b64 P writes
        #pragma unroll
        for (int g = 0; g < 2; g++) {
            #pragma unroll
            for (int mt = 0; mt < 4; mt++) {
                f32x4 sa = (f32x4){0.f, 0.f, 0.f, 0.f};
                #pragma unroll
                for (int s = 0; s < 2; s++)
                    sa = __builtin_amdgcn_mfma_f32_16x16x32_bf16(ak[mt][s], bq[g][s], sa, 0, 0, 0);
                float p0 = __expf(sa[0]);
                float p1 = __expf(sa[1]);
                float p2 = __expf(sa[2]);
                float p3 = __expf(sa[3]);
                lsum[g] += (p0 + p1) + (p2 + p3);
                uint2 pk;
                pk.x = (unsigned)f2bf(p0) | ((unsigned)f2bf(p1) << 16);
                pk.y = (unsigned)f2bf(p2) | ((unsigned)f2bf(p3) << 16);
                *(uint2*)&Ps[(g * 16 + c15) * 64 + ((mt * 16 + quad * 4) ^ swz)] = pk;
            }
        }

        // O += P V (P per-wave: same-wave DS ordering, no barrier)
        bf16x8 bv[4][2];
        #pragma unroll
        for (int nt = 0; nt < 4; nt++)
            #pragma unroll
            for (int s = 0; s < 2; s++)
                bv[nt][s] = *(bf16x8*)&Vs[(nt * 16 + c15) * 64 + quad * 8 + s * 32];
        #pragma unroll
        for (int g = 0; g < 2; g++)
            #pragma unroll
            for (int s = 0; s < 2; s++) {
                bf16x8 ap = *(bf16x8*)&Ps[(g * 16 + c15) * 64 + ((quad * 8 + s * 32) ^ swz)];
                #pragma unroll
                for (int nt = 0; nt < 4; nt++)
                    Oacc[g][nt] = __builtin_amdgcn_mfma_f32_16x16x32_bf16(
                        ap, bv[nt][s], Oacc[g][nt], 0, 0, 0);
            }

        if (pf) {   // stage tile tau+1 into the alternate buffer
            unsigned short* Kn = Sm + (1 - cur) * 8192;
            #pragma unroll
            for (int p = 0; p < 2; p++) {
                int row = srow + p * 32;
                *(u16x8*)&Kn[row * 64 + scol]        = kreg[p];
                *(u16x8*)&Kn[4096 + row * 64 + scol] = vreg[p];
            }
        }
    }

    // row sums: reduce across quads; linv via shfl
    #pragma unroll
    for (int g = 0; g < 2; g++) {
        lsum[g] += __shfl_xor(lsum[g], 16);
        lsum[g] += __shfl_xor(lsum[g], 32);
    }
    float linv[2][4];
    #pragma unroll
    for (int g = 0; g < 2; g++)
        #pragma unroll
        for (int r = 0; r < 4; r++)
            linv[g][r] = 1.0f / __shfl(lsum[g], quad * 4 + r);

    // epilogue: per-wave transpose through LDS ([64][36] f32 per wave)
    __syncthreads();   // all waves done with K/V/P reads
    float* Osw = (float*)(void*)Sm + wv * 2304;
    #pragma unroll
    for (int g = 0; g < 2; g++)
        #pragma unroll
        for (int nt = 0; nt < 4; nt++)
            #pragma unroll
            for (int r = 0; r < 4; r++)
                Osw[(nt * 16 + c15) * 36 + g * 16 + quad * 4 + r] =
                    Oacc[g][nt][r] * linv[g][r];

    const int b = bh >> 4, h = bh & 15;
    float* og = out + (size_t)b * D_ * T_ + (size_t)(h * DH_) * T_ + t0 + wv * 32;
    #pragma unroll
    for (int p = 0; p < 8; p++) {
        int idx = lane + p * 64;
        int dh  = idx >> 3;          // 0..63
        int qs  = (idx & 7) * 4;     // 0..28
        float4 v = *(float4*)&Osw[dh * 36 + qs];
        *(float4*)(og + (size_t)dh * T_ + qs) = v;
    }
}

extern "C" void kernel_launch(void* const* d_in, const int* in_sizes, int n_in,
                              void* d_out, int out_size, void* d_ws, size_t ws_size,
                              hipStream_t stream)
{
    const float* x = (const float*)d_in[0];   // (B, D, T) fp32
    const float* w = (const float*)d_in[1];   // (3, H, D, Dh) fp32
    float* out = (float*)d_out;               // (B, D, T) fp32

    // ws layout:
    unsigned short* qk = (unsigned short*)d_ws;                           // [2][32][T][64] bf16 = 16 MB (+8 MB slack)
    unsigned short* vT = (unsigned short*)((char*)d_ws + (24u << 20));    // [32][64][T] bf16 = 8 MB
    unsigned short* xT = (unsigned short*)((char*)d_ws + (32u << 20));    // [B][T][D] bf16 = 8 MB
    unsigned short* wT = (unsigned short*)((char*)d_ws + (40u << 20));    // [3][H][64][D] bf16 = 6 MB

    xpose_kernel<<<dim3(T_ / 64, D_ / 64, B_), 256, 0, stream>>>(x, xT);
    wpose_kernel<<<dim3(D_ / 64, 3 * H_), 256, 0, stream>>>(w, wT);
    proj_mfma_kernel<<<dim3(T_ / 128, 48), 256, 0, stream>>>(xT, wT, qk, vT);
    attn_mfma_kernel<<<512, 256, 0, stream>>>(qk, vT, out);
}

// Round 10
// 173.552 us; speedup vs baseline: 2.0015x; 1.0129x over previous
//
#include <hip/hip_runtime.h>

#define B_ 2
#define D_ 1024
#define T_ 2048
#define H_ 16
#define DH_ 64
#define BH_ (B_ * H_)

typedef __attribute__((ext_vector_type(8))) short bf16x8;
typedef __attribute__((ext_vector_type(8))) unsigned short u16x8;
typedef __attribute__((ext_vector_type(4))) float f32x4;

// float -> bf16 (RNE) as raw ushort
__device__ __forceinline__ unsigned short f2bf(float f) {
    unsigned u = __float_as_uint(f);
    u += 0x7fffu + ((u >> 16) & 1u);
    return (unsigned short)(u >> 16);
}

// ---------------------------------------------------------------------------
// Kernel T1: x (B,D,T) fp32 -> xT (B,T,D) bf16.  64x64 tiles through LDS.
// ---------------------------------------------------------------------------
__global__ __launch_bounds__(256) void xpose_kernel(
    const float* __restrict__ x, unsigned short* __restrict__ xT)
{
    __shared__ __align__(16) unsigned short Ls[64][68];
    const int t0 = blockIdx.x * 64;
    const int d0 = blockIdx.y * 64;
    const int b  = blockIdx.z;
    const int tid = threadIdx.x;

    const float* xb = x + (size_t)b * D_ * T_ + (size_t)d0 * T_ + t0;
    #pragma unroll
    for (int p = 0; p < 4; p++) {
        int i4  = tid + p * 256;
        int row = i4 >> 4;            // d
        int c4  = (i4 & 15) << 2;     // t
        float4 v = *(const float4*)(xb + (size_t)row * T_ + c4);
        ushort4 u;
        u.x = f2bf(v.x); u.y = f2bf(v.y); u.z = f2bf(v.z); u.w = f2bf(v.w);
        *(ushort4*)&Ls[row][c4] = u;
    }
    __syncthreads();
    unsigned short* ob = xT + (size_t)b * T_ * D_ + (size_t)t0 * D_ + d0;
    #pragma unroll
    for (int p = 0; p < 2; p++) {
        int i    = tid + p * 256;
        int orow = i >> 3;            // t
        int oc8  = (i & 7) * 8;       // d
        u16x8 tv;
        #pragma unroll
        for (int j = 0; j < 8; j++) tv[j] = Ls[oc8 + j][orow];
        *(u16x8*)(ob + (size_t)orow * D_ + oc8) = tv;
    }
}

// ---------------------------------------------------------------------------
// Kernel T2: w (3,H,D,Dh) fp32 -> wT (3,H,Dh,D) bf16.  64x64 tiles.
// ---------------------------------------------------------------------------
__global__ __launch_bounds__(256) void wpose_kernel(
    const float* __restrict__ w, unsigned short* __restrict__ wT)
{
    __shared__ __align__(16) unsigned short Ls[64][68];
    const int d0 = blockIdx.x * 64;
    const int nh = blockIdx.y;        // 0..47
    const int tid = threadIdx.x;

    const float* wb = w + (size_t)nh * D_ * DH_ + (size_t)d0 * DH_;
    #pragma unroll
    for (int p = 0; p < 4; p++) {
        int i4  = tid + p * 256;
        int row = i4 >> 4;            // d
        int c4  = (i4 & 15) << 2;     // dh
        float4 v = *(const float4*)(wb + (size_t)row * DH_ + c4);
        ushort4 u;
        u.x = f2bf(v.x); u.y = f2bf(v.y); u.z = f2bf(v.z); u.w = f2bf(v.w);
        *(ushort4*)&Ls[row][c4] = u;
    }
    __syncthreads();
    unsigned short* ob = wT + (size_t)nh * DH_ * D_ + d0;
    #pragma unroll
    for (int p = 0; p < 2; p++) {
        int i    = tid + p * 256;
        int orow = i >> 3;            // dh
        int oc8  = (i & 7) * 8;       // d
        u16x8 tv;
        #pragma unroll
        for (int j = 0; j < 8; j++) tv[j] = Ls[oc8 + j][orow];
        *(u16x8*)(ob + (size_t)orow * D_ + oc8) = tv;
    }
}

// ---------------------------------------------------------------------------
// Kernel G: QKV projection via bf16 MFMA, 128(t) x 128(dh = 2 heads) tiles.
// (unchanged from round 9 — proven)
// ---------------------------------------------------------------------------
#define LX 80

__global__ __launch_bounds__(256, 3) void proj_mfma_kernel(
    const unsigned short* __restrict__ xT, const unsigned short* __restrict__ wT,
    unsigned short* __restrict__ qk, unsigned short* __restrict__ vT)
{
    __shared__ __align__(16) unsigned short Buf[20480];  // 40960 B
    unsigned short* Xs = Buf;           // [128][80]
    unsigned short* Ws = Buf + 10240;   // [128][80]
    unsigned short* Es = Buf;           // [128][136] epilogue

    const int t0 = blockIdx.x * 128;
    const int y  = blockIdx.y;        // n*16 + b*8 + hp
    const int n  = y >> 4;
    const int b  = (y >> 3) & 1;
    const int hp = y & 7;             // head pair: heads 2hp, 2hp+1

    const unsigned short* xb = xT + (size_t)b * T_ * D_ + (size_t)t0 * D_;
    const unsigned short* wb = wT + (size_t)(n * 16 + 2 * hp) * DH_ * D_;

    const int tid  = threadIdx.x;
    const int wv   = tid >> 6;
    const int lane = tid & 63;
    const int c15  = lane & 15;
    const int quad = lane >> 4;
    const int tq   = (wv & 1) * 64;   // wave's t base
    const int dq   = (wv >> 1) * 64;  // wave's dh base

    const int srow = tid >> 3;        // 0..31
    const int scol = (tid & 7) * 8;   // 0..56

    f32x4 acc[4][4];
    #pragma unroll
    for (int mt = 0; mt < 4; mt++)
        #pragma unroll
        for (int nt = 0; nt < 4; nt++)
            acc[mt][nt] = (f32x4){0.f, 0.f, 0.f, 0.f};

    // prefetch tile k0=0
    u16x8 xreg[4], wreg[4];
    #pragma unroll
    for (int p = 0; p < 4; p++) {
        int row = srow + p * 32;
        xreg[p] = *(const u16x8*)(xb + (size_t)row * D_ + scol);
        wreg[p] = *(const u16x8*)(wb + (size_t)row * D_ + scol);
    }

    for (int k0 = 0; k0 < D_; k0 += 64) {
        __syncthreads();   // previous compute done reading Xs/Ws
        #pragma unroll
        for (int p = 0; p < 4; p++) {
            int row = srow + p * 32;
            *(u16x8*)&Xs[row * LX + scol] = xreg[p];
            *(u16x8*)&Ws[row * LX + scol] = wreg[p];
        }
        __syncthreads();   // tile staged

        if (k0 + 64 < D_) {
            #pragma unroll
            for (int p = 0; p < 4; p++) {
                int row = srow + p * 32;
                xreg[p] = *(const u16x8*)(xb + (size_t)row * D_ + k0 + 64 + scol);
                wreg[p] = *(const u16x8*)(wb + (size_t)row * D_ + k0 + 64 + scol);
            }
        }

        bf16x8 af[4][2], bf[4][2];
        #pragma unroll
        for (int mt = 0; mt < 4; mt++)
            #pragma unroll
            for (int s = 0; s < 2; s++)
                af[mt][s] = *(bf16x8*)&Xs[(tq + mt * 16 + c15) * LX + quad * 8 + s * 32];
        #pragma unroll
        for (int nt = 0; nt < 4; nt++)
            #pragma unroll
            for (int s = 0; s < 2; s++)
                bf[nt][s] = *(bf16x8*)&Ws[(dq + nt * 16 + c15) * LX + quad * 8 + s * 32];

        #pragma unroll
        for (int mt = 0; mt < 4; mt++)
            #pragma unroll
            for (int nt = 0; nt < 4; nt++)
                #pragma unroll
                for (int s = 0; s < 2; s++)
                    acc[mt][nt] = __builtin_amdgcn_mfma_f32_16x16x32_bf16(
                        af[mt][s], bf[nt][s], acc[mt][nt], 0, 0, 0);
    }

    const float scale = (n == 0) ? 0.125f : 1.0f;   // fold 1/sqrt(Dh) into q
    __syncthreads();   // done reading Xs/Ws
    #pragma unroll
    for (int mt = 0; mt < 4; mt++)
        #pragma unroll
        for (int nt = 0; nt < 4; nt++)
            #pragma unroll
            for (int r = 0; r < 4; r++)
                Es[(tq + mt * 16 + quad * 4 + r) * 136 + dq + nt * 16 + c15] =
                    f2bf(acc[mt][nt][r] * scale);
    __syncthreads();

    if (n < 2) {
        #pragma unroll
        for (int p = 0; p < 8; p++) {
            int i    = tid + p * 256;
            int row  = i >> 4;            // t 0..127
            int col8 = (i & 15) * 8;      // dh 0..120
            int head = col8 >> 6;
            unsigned short* ob = qk +
                ((size_t)(n * 32 + b * 16 + 2 * hp + head) * T_ + t0 + row) * DH_ + (col8 & 63);
            *(u16x8*)ob = *(u16x8*)&Es[row * 136 + col8];
        }
    } else {
        // v: transposed read-out -> vT[bh][dh][t]
        #pragma unroll
        for (int p = 0; p < 8; p++) {
            int i    = tid + p * 256;
            int orow = i >> 4;            // dh 0..127
            int oc8  = (i & 15) * 8;      // t 0..120
            int head = orow >> 6;
            u16x8 tv;
            #pragma unroll
            for (int j = 0; j < 8; j++) tv[j] = Es[(oc8 + j) * 136 + orow];
            unsigned short* ob = vT +
                (size_t)(b * 16 + 2 * hp + head) * DH_ * T_ +
                (size_t)(orow & 63) * T_ + t0 + oc8;
            *(u16x8*)ob = tv;
        }
    }
}

// ---------------------------------------------------------------------------
// Kernel A: flash attention, bf16 MFMA, fixed-max softmax.
// 64-q blocks (grid 1024 -> 4 blocks/CU, 16 waves/CU), 4 waves, 16 q/wave.
// K/V double-buffered, XOR-SWIZZLED tiles: 16-B chunk c of row r stored at
// chunk c ^ (r&7) -> all fragment reads spread across 32 banks (2-way max).
// Single barrier per iteration with register prefetch. P per-wave [16][64],
// XOR-swizzled (round-9 proven formula). LDS 40960 B -> 4 blocks/CU.
// ---------------------------------------------------------------------------
__global__ __launch_bounds__(256, 4) void attn_mfma_kernel(
    const unsigned short* __restrict__ qk, const unsigned short* __restrict__ vT,
    float* __restrict__ out)
{
    // shorts: K0[0,4096) V0[4096,8192) K1[8192,12288) V1[12288,16384)
    //         P 4 x [16][64] at [16384,20480).  Total 40960 B.
    __shared__ __align__(16) unsigned short Sm[20480];

    const int flat = blockIdx.x;                            // 0..1023
    const int bh   = (flat & 7) * 4 + ((flat >> 3) >> 5);   // XCD swizzle: 4 bh/XCD
    const int t0   = ((flat >> 3) & 31) * 64;

    const unsigned short* qg = qk + ((size_t)bh * T_ + t0) * DH_;   // pre-scaled q
    const unsigned short* kg = qk + ((size_t)(BH_ + bh) * T_) * DH_;
    const unsigned short* vg = vT + (size_t)bh * DH_ * T_;          // [dh][t]

    const int tid  = threadIdx.x;
    const int wv   = tid >> 6;
    const int lane = tid & 63;
    const int c15  = lane & 15;
    const int quad = lane >> 4;
    const int swz  = (c15 & 7) * 8;   // P-column swizzle (shorts)
    const int h7   = c15 & 7;         // K/V chunk swizzle key

    unsigned short* Ps = Sm + 16384 + wv * 1024;   // [16][64]

    const int srow = tid >> 3;        // staging row 0..31
    const int sch  = tid & 7;         // staging logical chunk 0..7
    const int ssw  = ((sch ^ (srow & 7)) * 8);   // swizzled short offset in row

    // Q^T B-fragments straight from global: wave owns q rows wv*16..+16
    bf16x8 bq[2];
    #pragma unroll
    for (int s = 0; s < 2; s++)
        bq[s] = *(const bf16x8*)(qg + (size_t)(wv * 16 + c15) * DH_ + quad * 8 + s * 32);

    float lsum = 0.f;
    f32x4 Oacc[4];
    #pragma unroll
    for (int nt = 0; nt < 4; nt++) Oacc[nt] = (f32x4){0.f, 0.f, 0.f, 0.f};

    // preload tile 0 and stage into buffer 0 (no prior readers)
    u16x8 kreg[2], vreg[2];
    #pragma unroll
    for (int p = 0; p < 2; p++) {
        int row = srow + p * 32;
        kreg[p] = *(const u16x8*)(kg + (size_t)row * DH_ + sch * 8);
        vreg[p] = *(const u16x8*)(vg + (size_t)row * T_ + sch * 8);
    }
    #pragma unroll
    for (int p = 0; p < 2; p++) {
        int row = srow + p * 32;
        *(u16x8*)&Sm[row * 64 + ssw]        = kreg[p];
        *(u16x8*)&Sm[4096 + row * 64 + ssw] = vreg[p];
    }

    for (int tau = 0; tau < T_; tau += 64) {
        const int cur = (tau >> 6) & 1;
        unsigned short* Ks = Sm + cur * 8192;
        unsigned short* Vs = Ks + 4096;
        __syncthreads();   // tile tau staged by all waves; buf[1-cur] free

        const bool pf = (tau + 64 < T_);
        if (pf) {   // issue global loads for tile tau+1 early
            #pragma unroll
            for (int p = 0; p < 2; p++) {
                int row = srow + p * 32;
                kreg[p] = *(const u16x8*)(kg + (size_t)(tau + 64 + row) * DH_ + sch * 8);
                vreg[p] = *(const u16x8*)(vg + (size_t)row * T_ + tau + 64 + sch * 8);
            }
        }

        // S^T = K Q^T per 16-key block; exp; swizzled b64 write to own-wave Ps
        #pragma unroll
        for (int mt = 0; mt < 4; mt++) {
            f32x4 sa = (f32x4){0.f, 0.f, 0.f, 0.f};
            #pragma unroll
            for (int s = 0; s < 2; s++) {
                bf16x8 ak = *(bf16x8*)&Ks[(mt * 16 + c15) * 64 +
                                          (((quad + 4 * s) ^ h7) * 8)];
                sa = __builtin_amdgcn_mfma_f32_16x16x32_bf16(ak, bq[s], sa, 0, 0, 0);
            }
            float p0 = __expf(sa[0]);
            float p1 = __expf(sa[1]);
            float p2 = __expf(sa[2]);
            float p3 = __expf(sa[3]);
            lsum += (p0 + p1) + (p2 + p3);
            uint2 pk;
            pk.x = (unsigned)f2bf(p0) | ((unsigned)f2bf(p1) << 16);
            pk.y = (unsigned)f2bf(p2) | ((unsigned)f2bf(p3) << 16);
            *(uint2*)&Ps[c15 * 64 + ((mt * 16 + quad * 4) ^ swz)] = pk;
        }
        // no barrier: Ps per-wave, same-wave DS ordering

        // O += P V : A = P rows (swizzled b128), B = V^T fragments (swizzled)
        #pragma unroll
        for (int s = 0; s < 2; s++) {
            bf16x8 ap = *(bf16x8*)&Ps[c15 * 64 + ((quad * 8 + s * 32) ^ swz)];
            #pragma unroll
            for (int nt = 0; nt < 4; nt++) {
                bf16x8 bv = *(bf16x8*)&Vs[(nt * 16 + c15) * 64 +
                                          (((quad + 4 * s) ^ h7) * 8)];
                Oacc[nt] = __builtin_amdgcn_mfma_f32_16x16x32_bf16(ap, bv, Oacc[nt], 0, 0, 0);
            }
        }

        if (pf) {   // stage tile tau+1 into the alternate buffer
            unsigned short* Kn = Sm + (1 - cur) * 8192;
            #pragma unroll
            for (int p = 0; p < 2; p++) {
                int row = srow + p * 32;
                *(u16x8*)&Kn[row * 64 + ssw]        = kreg[p];
                *(u16x8*)&Kn[4096 + row * 64 + ssw] = vreg[p];
            }
        }
    }

    // row sums: reduce across quads; linv via shfl
    lsum += __shfl_xor(lsum, 16);
    lsum += __shfl_xor(lsum, 32);
    float linv[4];
    #pragma unroll
    for (int r = 0; r < 4; r++)
        linv[r] = 1.0f / __shfl(lsum, quad * 4 + r);

    // epilogue: per-wave transpose through LDS ([64][17] f32 per wave)
    __syncthreads();   // all waves done with K/V/P reads
    float* Osw = (float*)(void*)Sm + wv * 1088;
    #pragma unroll
    for (int nt = 0; nt < 4; nt++)
        #pragma unroll
        for (int r = 0; r < 4; r++)
            Osw[(nt * 16 + c15) * 17 + quad * 4 + r] = Oacc[nt][r] * linv[r];

    const int b = bh >> 4, h = bh & 15;
    float* og = out + (size_t)b * D_ * T_ + (size_t)(h * DH_) * T_ + t0 + wv * 16;
    #pragma unroll
    for (int p = 0; p < 4; p++) {
        int idx = lane + p * 64;
        int dh  = idx >> 2;          // 0..63
        int qs  = (idx & 3) * 4;     // 0,4,8,12
        float4 v = *(float4*)&Osw[dh * 17 + qs];
        *(float4*)(og + (size_t)dh * T_ + qs) = v;
    }
}

extern "C" void kernel_launch(void* const* d_in, const int* in_sizes, int n_in,
                              void* d_out, int out_size, void* d_ws, size_t ws_size,
                              hipStream_t stream)
{
    const float* x = (const float*)d_in[0];   // (B, D, T) fp32
    const float* w = (const float*)d_in[1];   // (3, H, D, Dh) fp32
    float* out = (float*)d_out;               // (B, D, T) fp32

    // ws layout:
    unsigned short* qk = (unsigned short*)d_ws;                           // [2][32][T][64] bf16 = 16 MB (+8 MB slack)
    unsigned short* vT = (unsigned short*)((char*)d_ws + (24u << 20));    // [32][64][T] bf16 = 8 MB
    unsigned short* xT = (unsigned short*)((char*)d_ws + (32u << 20));    // [B][T][D] bf16 = 8 MB
    unsigned short* wT = (unsigned short*)((char*)d_ws + (40u << 20));    // [3][H][64][D] bf16 = 6 MB

    xpose_kernel<<<dim3(T_ / 64, D_ / 64, B_), 256, 0, stream>>>(x, xT);
    wpose_kernel<<<dim3(D_ / 64, 3 * H_), 256, 0, stream>>>(w, wT);
    proj_mfma_kernel<<<dim3(T_ / 128, 48), 256, 0, stream>>>(xT, wT, qk, vT);
    attn_mfma_kernel<<<1024, 256, 0, stream>>>(qk, vT, out);
}